// Round 7
// baseline (259.718 us; speedup 1.0000x reference)
//
#include <hip/hip_runtime.h>

#define BB 4
#define CIN 32
#define COUT 32
#define TT 48
#define NN 2000
#define EE 16000
#define BT (BB*TT)
#define PADCOL 24576   // padded CSR capacity (16000 + 2000*3 = 22000 max)

// ---- build: counts, scan, rowptr, degree terms, weight prep -------------

__global__ __launch_bounds__(1024) void k_build(
        const int* __restrict__ ei,
        const float* __restrict__ w1, const float* __restrict__ gw,
        const float* __restrict__ gb, const float* __restrict__ w2,
        int* __restrict__ rowptr, float* __restrict__ dinv2,
        float* __restrict__ dinvg, int* __restrict__ fillptr,
        int* __restrict__ col, float* __restrict__ wedge,
        float* __restrict__ w1t, float* __restrict__ w2c,
        float* __restrict__ bias2) {
    __shared__ int   cnt[2048];
    __shared__ int   buf[2048];
    __shared__ float sw2t[3072];   // [k][co][c] transposed w2
    __shared__ float sgw[1024];
    int t = threadIdx.x;

    // 0. stage weights; write w1t (transpose) directly
    for (int i = t; i < 3072; i += 1024) {
        int c = i & 31, r = i >> 5;
        int co = r & 31, k = r >> 5;           // i = (k*32+co)*32 + c
        sw2t[i] = w2[c * 96 + co * 3 + k];
        w1t[i]  = w1[c * 96 + co * 3 + k];
    }
    sgw[t] = gw[t];
    cnt[t] = 0; cnt[t + 1024] = 0;
    __syncthreads();

    // 1. count in-degrees (LDS atomics)
    for (int e = t; e < EE; e += 1024) atomicAdd(&cnt[ei[EE + e]], 1);
    __syncthreads();

    // 2. inclusive scan over PADDED counts (rows padded to multiple of 4)
    for (int i = t; i < 2048; i += 1024)
        buf[i] = (i < NN) ? ((cnt[i] + 3) & ~3) : 0;
    __syncthreads();
    for (int s = 1; s < 2048; s <<= 1) {
        int i0 = t, i1 = t + 1024;
        int a0 = buf[i0] + ((i0 >= s) ? buf[i0 - s] : 0);
        int a1 = buf[i1] + ((i1 >= s) ? buf[i1 - s] : 0);
        __syncthreads();
        buf[i0] = a0; buf[i1] = a1;
        __syncthreads();
    }

    // 3. rowptr + degree terms + global fill pointers
    for (int i = t; i < 2048; i += 1024) {
        if (i < NN) {
            rowptr[i + 1] = buf[i];
            float deg = (float)(cnt[i] + 1);
            dinvg[i] = rsqrtf(deg);
            dinv2[i] = 1.0f / deg;
            fillptr[i] = buf[i] - ((cnt[i] + 3) & ~3);  // padded row start
        }
    }
    if (t == 0) rowptr[0] = 0;

    // 4. zero padded col/wedge (P <= PADCOL)
    int P = buf[NN - 1];
    __syncthreads();
    for (int i = t; i < P; i += 1024) { col[i] = 0; wedge[i] = 0.f; }

    // 5. compose w2c[k][cm][c] = sum_co gw[cm][co] * w2t[k][co][c]  (all LDS)
    for (int i = t; i < 3072; i += 1024) {
        int c = i & 31, r = i >> 5;
        int cm = r & 31, k = r >> 5;
        float acc = 0.f;
#pragma unroll
        for (int co = 0; co < 32; co++)
            acc += sgw[cm * 32 + co] * sw2t[(k * 32 + co) * 32 + c];
        w2c[i] = acc;
    }
    for (int i = t; i < 96; i += 1024) {
        int k = i >> 5, c = i & 31;
        float acc = 0.f;
#pragma unroll
        for (int co = 0; co < 32; co++)
            acc += gb[co] * sw2t[(k * 32 + co) * 32 + c];
        bias2[i] = acc;
    }
}

// ---- edge fill: parallel across CUs (device-scope atomics) --------------

__global__ void k_fill(const int* __restrict__ ei, int* __restrict__ fillptr,
                       const float* __restrict__ dinvg,
                       int* __restrict__ col, float* __restrict__ wedge) {
    int e = blockIdx.x * blockDim.x + threadIdx.x;
    if (e < EE) {
        int s = ei[e], d = ei[EE + e];
        int pos = atomicAdd(fillptr + d, 1);
        col[pos]   = s;
        wedge[pos] = dinvg[s] * dinvg[d];
    }
}

// ---- conv1: temporal conv + relu -> hbuf BUNDLED [gb][n][gsub][c] -------
// R5 compiled to a serial load->use chain (VGPR 36, one x value buffered).
// Now: per tap, batch-load all 32 x values into xv[] (independent loads,
// one vmcnt drain), THEN the 1024 FMAs. Latency paid once per tap.

__global__ __launch_bounds__(256) void k_conv1(const float* __restrict__ x,
                                               const float* __restrict__ w1t,
                                               const float* __restrict__ b1,
                                               float* __restrict__ hbuf) {
    int n = blockIdx.x * 256 + threadIdx.x;
    if (n >= NN) return;
    int t = blockIdx.y, b = blockIdx.z;
    int g = b * TT + t;
    int gb = g >> 3, gsub = g & 7;

    float ha[COUT];
#pragma unroll
    for (int c = 0; c < COUT; c++) ha[c] = b1[c];

    for (int k = 0; k < 3; k++) {
        int tt = t + k - 1;
        if (tt < 0 || tt >= TT) continue;
        const float* xb = x + (((size_t)b * CIN) * TT + tt) * NN + n;

        float xv[CIN];
#pragma unroll
        for (int ci = 0; ci < CIN; ci++)
            xv[ci] = xb[(size_t)ci * TT * NN];   // 32 independent loads

        const float* wp = w1t + k * CIN * COUT;
#pragma unroll
        for (int ci = 0; ci < CIN; ci++) {
#pragma unroll
            for (int c = 0; c < COUT; c++) ha[c] += xv[ci] * wp[ci * COUT + c];
        }
    }

    float4* pa = (float4*)(hbuf + (((size_t)gb * NN + n) * 8 + gsub) * 32);
#pragma unroll
    for (int q = 0; q < 8; q++)
        pa[q] = make_float4(fmaxf(ha[4*q], 0.f), fmaxf(ha[4*q+1], 0.f),
                            fmaxf(ha[4*q+2], 0.f), fmaxf(ha[4*q+3], 0.f));
}

// ---- GCN aggregate, graph-bundled (unchanged: out of top-5) -------------

__global__ __launch_bounds__(256) void k_agg(const float* __restrict__ hbuf,
                                             const int* __restrict__ rowptr,
                                             const int* __restrict__ col,
                                             const float* __restrict__ wedge,
                                             const float* __restrict__ dinv2,
                                             float* __restrict__ gbuf) {
    // 12000 blocks: 8 xcd-slots x 3 bundle-rows x 500 node-quads
    int bid = blockIdx.x;
    int xcd = bid & 7;
    int q   = bid >> 3;
    int gbr = q / 500;
    int nch = q % 500;
    int gb  = gbr * 8 + xcd;
    int wid  = threadIdx.x >> 6;
    int lane = threadIdx.x & 63;
    int gsub = lane >> 3;
    int cq   = lane & 7;
    int n    = nch * 4 + wid;

    const float* xg = hbuf + (size_t)gb * NN * 256;
    size_t loff = (size_t)gsub * 32 + cq * 4;

    float4 self = *(const float4*)(xg + (size_t)n * 256 + loff);
    float dv = dinv2[n];
    float4 acc = make_float4(dv * self.x, dv * self.y, dv * self.z, dv * self.w);

    int j  = rowptr[n];
    int je = rowptr[n + 1];
    for (; j < je; j += 4) {
        int4   cc = *(const int4*)(col + j);
        float4 ww = *(const float4*)(wedge + j);
        float4 v0 = *(const float4*)(xg + (size_t)cc.x * 256 + loff);
        float4 v1 = *(const float4*)(xg + (size_t)cc.y * 256 + loff);
        float4 v2 = *(const float4*)(xg + (size_t)cc.z * 256 + loff);
        float4 v3 = *(const float4*)(xg + (size_t)cc.w * 256 + loff);
        acc.x += ww.x*v0.x + ww.y*v1.x + ww.z*v2.x + ww.w*v3.x;
        acc.y += ww.x*v0.y + ww.y*v1.y + ww.z*v2.y + ww.w*v3.y;
        acc.z += ww.x*v0.z + ww.y*v1.z + ww.z*v2.z + ww.w*v3.z;
        acc.w += ww.x*v0.w + ww.y*v1.w + ww.z*v2.w + ww.w*v3.w;
    }

    int g = gb * 8 + gsub;
    *(float4*)(gbuf + ((size_t)g * NN + n) * 32 + cq * 4) = acc;
}

// ---- conv2 with composed weights (reads standard [g][n][c]) -------------

__global__ __launch_bounds__(256) void k_conv2(const float* __restrict__ gbuf,
                                               const float* __restrict__ w2c,
                                               const float* __restrict__ bias2,
                                               const float* __restrict__ b2,
                                               float* __restrict__ out) {
    int n = blockIdx.x * 256 + threadIdx.x;
    if (n >= NN) return;
    int t = blockIdx.y, b = blockIdx.z;

    float o[COUT];
#pragma unroll
    for (int c = 0; c < COUT; c++) o[c] = b2[c];

    for (int k = 0; k < 3; k++) {
        int tt = t + k - 1;
        if (tt < 0 || tt >= TT) continue;
        const float4* gp = (const float4*)(gbuf + (((size_t)(b * TT + tt)) * NN + n) * CIN);
        const float* wp = w2c + k * CIN * COUT;
        const float* bp = bias2 + k * COUT;
        float gv[CIN];
#pragma unroll
        for (int qq = 0; qq < 8; qq++) {
            float4 v = gp[qq];
            gv[4*qq] = v.x; gv[4*qq+1] = v.y; gv[4*qq+2] = v.z; gv[4*qq+3] = v.w;
        }
#pragma unroll
        for (int c = 0; c < COUT; c++) o[c] += bp[c];
#pragma unroll
        for (int cm = 0; cm < CIN; cm++) {
#pragma unroll
            for (int c = 0; c < COUT; c++) o[c] += gv[cm] * wp[cm * COUT + c];
        }
    }

#pragma unroll
    for (int c = 0; c < COUT; c++)
        out[(((size_t)b * COUT + c) * TT + t) * NN + n] = o[c];
}

// ---- launch -------------------------------------------------------------

extern "C" void kernel_launch(void* const* d_in, const int* in_sizes, int n_in,
                              void* d_out, int out_size, void* d_ws, size_t ws_size,
                              hipStream_t stream) {
    const float* x     = (const float*)d_in[0];
    const int*   ei    = (const int*)d_in[1];
    const float* w1    = (const float*)d_in[2];
    const float* b1    = (const float*)d_in[3];
    const float* gcn_w = (const float*)d_in[4];
    const float* gcn_b = (const float*)d_in[5];
    const float* w2    = (const float*)d_in[6];
    const float* b2    = (const float*)d_in[7];
    float* out = (float*)d_out;

    const size_t XWB = (size_t)BT * NN * COUT * sizeof(float);  // 49.152 MB
    char* w = (char*)d_ws;
    float* hbuf    = (float*)w;  w += XWB;   // bundled [gb][n][gsub][c]
    float* gbuf    = (float*)w;  w += XWB;   // standard [g][n][c]
    int*   rowptr  = (int*)w;    w += 8192;
    float* dinv2   = (float*)w;  w += 8192;
    float* dinvg   = (float*)w;  w += 8192;
    int*   fillptr = (int*)w;    w += 8192;
    int*   col     = (int*)w;    w += PADCOL * sizeof(int);
    float* wedge   = (float*)w;  w += PADCOL * sizeof(float);
    float* w1t     = (float*)w;  w += 3072 * sizeof(float);
    float* w2c     = (float*)w;  w += 3072 * sizeof(float);
    float* bias2   = (float*)w;  w += 96 * sizeof(float);

    k_build<<<dim3(1), dim3(1024), 0, stream>>>(ei, w1, gcn_w, gcn_b, w2,
                                                rowptr, dinv2, dinvg, fillptr,
                                                col, wedge, w1t, w2c, bias2);
    k_fill <<<dim3((EE + 255) / 256), dim3(256), 0, stream>>>(ei, fillptr, dinvg, col, wedge);
    k_conv1<<<dim3(8, TT, BB), dim3(256), 0, stream>>>(x, w1t, b1, hbuf);
    k_agg  <<<dim3(12000), dim3(256), 0, stream>>>(hbuf, rowptr, col, wedge, dinv2, gbuf);
    k_conv2<<<dim3(8, TT, BB), dim3(256), 0, stream>>>(gbuf, w2c, bias2, b2, out);
}

// Round 8
// 248.037 us; speedup vs baseline: 1.0471x; 1.0471x over previous
//
#include <hip/hip_runtime.h>

#define BB 4
#define CIN 32
#define COUT 32
#define TT 48
#define NN 2000
#define EE 16000
#define BT (BB*TT)
#define PADCOL 24576   // padded CSR capacity (16000 + 2000*3 = 22000 max)

// ---- build: counts, scan, rowptr, degree terms, weight prep -------------

__global__ __launch_bounds__(1024) void k_build(
        const int* __restrict__ ei,
        const float* __restrict__ w1, const float* __restrict__ gw,
        const float* __restrict__ gb, const float* __restrict__ w2,
        int* __restrict__ rowptr, float* __restrict__ dinv2,
        float* __restrict__ dinvg, int* __restrict__ fillptr,
        int* __restrict__ col, float* __restrict__ wedge,
        float* __restrict__ w1t, float* __restrict__ w2c,
        float* __restrict__ bias2) {
    __shared__ int   cnt[2048];
    __shared__ int   buf[2048];
    __shared__ float sw2t[3072];   // [k][co][c] transposed w2
    __shared__ float sgw[1024];
    int t = threadIdx.x;

    // 0. stage weights; write w1t (transpose) directly
    for (int i = t; i < 3072; i += 1024) {
        int c = i & 31, r = i >> 5;
        int co = r & 31, k = r >> 5;           // i = (k*32+co)*32 + c
        sw2t[i] = w2[c * 96 + co * 3 + k];
        w1t[i]  = w1[c * 96 + co * 3 + k];
    }
    sgw[t] = gw[t];
    cnt[t] = 0; cnt[t + 1024] = 0;
    __syncthreads();

    // 1. count in-degrees (LDS atomics)
    for (int e = t; e < EE; e += 1024) atomicAdd(&cnt[ei[EE + e]], 1);
    __syncthreads();

    // 2. inclusive scan over PADDED counts (rows padded to multiple of 4)
    for (int i = t; i < 2048; i += 1024)
        buf[i] = (i < NN) ? ((cnt[i] + 3) & ~3) : 0;
    __syncthreads();
    for (int s = 1; s < 2048; s <<= 1) {
        int i0 = t, i1 = t + 1024;
        int a0 = buf[i0] + ((i0 >= s) ? buf[i0 - s] : 0);
        int a1 = buf[i1] + ((i1 >= s) ? buf[i1 - s] : 0);
        __syncthreads();
        buf[i0] = a0; buf[i1] = a1;
        __syncthreads();
    }

    // 3. rowptr + degree terms + global fill pointers
    for (int i = t; i < 2048; i += 1024) {
        if (i < NN) {
            rowptr[i + 1] = buf[i];
            float deg = (float)(cnt[i] + 1);
            dinvg[i] = rsqrtf(deg);
            dinv2[i] = 1.0f / deg;
            fillptr[i] = buf[i] - ((cnt[i] + 3) & ~3);  // padded row start
        }
    }
    if (t == 0) rowptr[0] = 0;

    // 4. zero padded col/wedge (P <= PADCOL)
    int P = buf[NN - 1];
    __syncthreads();
    for (int i = t; i < P; i += 1024) { col[i] = 0; wedge[i] = 0.f; }

    // 5. compose w2c[k][cm][c] = sum_co gw[cm][co] * w2t[k][co][c]  (all LDS)
    for (int i = t; i < 3072; i += 1024) {
        int c = i & 31, r = i >> 5;
        int cm = r & 31, k = r >> 5;
        float acc = 0.f;
#pragma unroll
        for (int co = 0; co < 32; co++)
            acc += sgw[cm * 32 + co] * sw2t[(k * 32 + co) * 32 + c];
        w2c[i] = acc;
    }
    for (int i = t; i < 96; i += 1024) {
        int k = i >> 5, c = i & 31;
        float acc = 0.f;
#pragma unroll
        for (int co = 0; co < 32; co++)
            acc += gb[co] * sw2t[(k * 32 + co) * 32 + c];
        bias2[i] = acc;
    }
}

// ---- edge fill: parallel across CUs (device-scope atomics) --------------

__global__ void k_fill(const int* __restrict__ ei, int* __restrict__ fillptr,
                       const float* __restrict__ dinvg,
                       int* __restrict__ col, float* __restrict__ wedge) {
    int e = blockIdx.x * blockDim.x + threadIdx.x;
    if (e < EE) {
        int s = ei[e], d = ei[EE + e];
        int pos = atomicAdd(fillptr + d, 1);
        col[pos]   = s;
        wedge[pos] = dinvg[s] * dinvg[d];
    }
}

// ---- conv1: temporal conv + relu -> hbuf BUNDLED [gb][n][gsub][c] -------
// R6 failed: compiler sank the xv[] loads back into the FMA loop (VGPR 40).
// Now sched_barrier(0) pins all 32 loads of a tap BEFORE the FMA block:
// latency paid ~once per tap instead of 32x. Grid XCD-swizzled so each
// XCD's L2 keeps a contiguous 6-t-slice window of x (tap-overlap reuse).

__global__ __launch_bounds__(256) void k_conv1(const float* __restrict__ x,
                                               const float* __restrict__ w1t,
                                               const float* __restrict__ b1,
                                               float* __restrict__ hbuf) {
    // 1536 blocks: xcd = bid&7 owns t in [xcd*6, xcd*6+6) for each b
    int bid = blockIdx.x;
    int xcd = bid & 7;
    int i   = bid >> 3;              // 0..191
    int nch = i & 7;                 // 8 chunks of 256 nodes
    int r   = i >> 3;                // 0..23
    int tloc = r % 6, b = r / 6;
    int t = xcd * 6 + tloc;
    int n = nch * 256 + threadIdx.x;
    if (n >= NN) return;
    int g = b * TT + t;
    int gb = g >> 3, gsub = g & 7;

    float ha[COUT];
#pragma unroll
    for (int c = 0; c < COUT; c++) ha[c] = b1[c];

    for (int k = 0; k < 3; k++) {
        int tt = t + k - 1;
        if (tt < 0 || tt >= TT) continue;
        const float* xb = x + (((size_t)b * CIN) * TT + tt) * NN + n;

        float xv[CIN];
#pragma unroll
        for (int ci = 0; ci < CIN; ci++)
            xv[ci] = xb[(size_t)ci * TT * NN];   // 32 independent loads
        __builtin_amdgcn_sched_barrier(0);        // loads may not sink below

        const float* wp = w1t + k * CIN * COUT;
#pragma unroll
        for (int ci = 0; ci < CIN; ci++) {
#pragma unroll
            for (int c = 0; c < COUT; c++) ha[c] += xv[ci] * wp[ci * COUT + c];
        }
        __builtin_amdgcn_sched_barrier(0);        // next tap's loads stay after
    }

    float4* pa = (float4*)(hbuf + (((size_t)gb * NN + n) * 8 + gsub) * 32);
#pragma unroll
    for (int q = 0; q < 8; q++)
        pa[q] = make_float4(fmaxf(ha[4*q], 0.f), fmaxf(ha[4*q+1], 0.f),
                            fmaxf(ha[4*q+2], 0.f), fmaxf(ha[4*q+3], 0.f));
}

// ---- GCN aggregate, graph-bundled (unchanged: out of top-5) -------------

__global__ __launch_bounds__(256) void k_agg(const float* __restrict__ hbuf,
                                             const int* __restrict__ rowptr,
                                             const int* __restrict__ col,
                                             const float* __restrict__ wedge,
                                             const float* __restrict__ dinv2,
                                             float* __restrict__ gbuf) {
    // 12000 blocks: 8 xcd-slots x 3 bundle-rows x 500 node-quads
    int bid = blockIdx.x;
    int xcd = bid & 7;
    int q   = bid >> 3;
    int gbr = q / 500;
    int nch = q % 500;
    int gb  = gbr * 8 + xcd;
    int wid  = threadIdx.x >> 6;
    int lane = threadIdx.x & 63;
    int gsub = lane >> 3;
    int cq   = lane & 7;
    int n    = nch * 4 + wid;

    const float* xg = hbuf + (size_t)gb * NN * 256;
    size_t loff = (size_t)gsub * 32 + cq * 4;

    float4 self = *(const float4*)(xg + (size_t)n * 256 + loff);
    float dv = dinv2[n];
    float4 acc = make_float4(dv * self.x, dv * self.y, dv * self.z, dv * self.w);

    int j  = rowptr[n];
    int je = rowptr[n + 1];
    for (; j < je; j += 4) {
        int4   cc = *(const int4*)(col + j);
        float4 ww = *(const float4*)(wedge + j);
        float4 v0 = *(const float4*)(xg + (size_t)cc.x * 256 + loff);
        float4 v1 = *(const float4*)(xg + (size_t)cc.y * 256 + loff);
        float4 v2 = *(const float4*)(xg + (size_t)cc.z * 256 + loff);
        float4 v3 = *(const float4*)(xg + (size_t)cc.w * 256 + loff);
        acc.x += ww.x*v0.x + ww.y*v1.x + ww.z*v2.x + ww.w*v3.x;
        acc.y += ww.x*v0.y + ww.y*v1.y + ww.z*v2.y + ww.w*v3.y;
        acc.z += ww.x*v0.z + ww.y*v1.z + ww.z*v2.z + ww.w*v3.z;
        acc.w += ww.x*v0.w + ww.y*v1.w + ww.z*v2.w + ww.w*v3.w;
    }

    int g = gb * 8 + gsub;
    *(float4*)(gbuf + ((size_t)g * NN + n) * 32 + cq * 4) = acc;
}

// ---- conv2 with composed weights (reads standard [g][n][c]) -------------

__global__ __launch_bounds__(256) void k_conv2(const float* __restrict__ gbuf,
                                               const float* __restrict__ w2c,
                                               const float* __restrict__ bias2,
                                               const float* __restrict__ b2,
                                               float* __restrict__ out) {
    int n = blockIdx.x * 256 + threadIdx.x;
    if (n >= NN) return;
    int t = blockIdx.y, b = blockIdx.z;

    float o[COUT];
#pragma unroll
    for (int c = 0; c < COUT; c++) o[c] = b2[c];

    for (int k = 0; k < 3; k++) {
        int tt = t + k - 1;
        if (tt < 0 || tt >= TT) continue;
        const float4* gp = (const float4*)(gbuf + (((size_t)(b * TT + tt)) * NN + n) * CIN);
        const float* wp = w2c + k * CIN * COUT;
        const float* bp = bias2 + k * COUT;
        float gv[CIN];
#pragma unroll
        for (int qq = 0; qq < 8; qq++) {
            float4 v = gp[qq];
            gv[4*qq] = v.x; gv[4*qq+1] = v.y; gv[4*qq+2] = v.z; gv[4*qq+3] = v.w;
        }
#pragma unroll
        for (int c = 0; c < COUT; c++) o[c] += bp[c];
#pragma unroll
        for (int cm = 0; cm < CIN; cm++) {
#pragma unroll
            for (int c = 0; c < COUT; c++) o[c] += gv[cm] * wp[cm * COUT + c];
        }
    }

#pragma unroll
    for (int c = 0; c < COUT; c++)
        out[(((size_t)b * COUT + c) * TT + t) * NN + n] = o[c];
}

// ---- launch -------------------------------------------------------------

extern "C" void kernel_launch(void* const* d_in, const int* in_sizes, int n_in,
                              void* d_out, int out_size, void* d_ws, size_t ws_size,
                              hipStream_t stream) {
    const float* x     = (const float*)d_in[0];
    const int*   ei    = (const int*)d_in[1];
    const float* w1    = (const float*)d_in[2];
    const float* b1    = (const float*)d_in[3];
    const float* gcn_w = (const float*)d_in[4];
    const float* gcn_b = (const float*)d_in[5];
    const float* w2    = (const float*)d_in[6];
    const float* b2    = (const float*)d_in[7];
    float* out = (float*)d_out;

    const size_t XWB = (size_t)BT * NN * COUT * sizeof(float);  // 49.152 MB
    char* w = (char*)d_ws;
    float* hbuf    = (float*)w;  w += XWB;   // bundled [gb][n][gsub][c]
    float* gbuf    = (float*)w;  w += XWB;   // standard [g][n][c]
    int*   rowptr  = (int*)w;    w += 8192;
    float* dinv2   = (float*)w;  w += 8192;
    float* dinvg   = (float*)w;  w += 8192;
    int*   fillptr = (int*)w;    w += 8192;
    int*   col     = (int*)w;    w += PADCOL * sizeof(int);
    float* wedge   = (float*)w;  w += PADCOL * sizeof(float);
    float* w1t     = (float*)w;  w += 3072 * sizeof(float);
    float* w2c     = (float*)w;  w += 3072 * sizeof(float);
    float* bias2   = (float*)w;  w += 96 * sizeof(float);

    k_build<<<dim3(1), dim3(1024), 0, stream>>>(ei, w1, gcn_w, gcn_b, w2,
                                                rowptr, dinv2, dinvg, fillptr,
                                                col, wedge, w1t, w2c, bias2);
    k_fill <<<dim3((EE + 255) / 256), dim3(256), 0, stream>>>(ei, fillptr, dinvg, col, wedge);
    k_conv1<<<dim3(1536), dim3(256), 0, stream>>>(x, w1t, b1, hbuf);
    k_agg  <<<dim3(12000), dim3(256), 0, stream>>>(hbuf, rowptr, col, wedge, dinv2, gbuf);
    k_conv2<<<dim3(8, TT, BB), dim3(256), 0, stream>>>(gbuf, w2c, bias2, b2, out);
}